// Round 11
// baseline (163.866 us; speedup 1.0000x reference)
//
#include <hip/hip_runtime.h>

typedef unsigned short u16;
typedef unsigned int u32;
typedef __bf16 bf16x8 __attribute__((ext_vector_type(8)));
typedef float f32x4 __attribute__((ext_vector_type(4)));
typedef int i32x4 __attribute__((ext_vector_type(4)));
typedef u32 u32x2 __attribute__((ext_vector_type(2)));
typedef u32 u32x4 __attribute__((ext_vector_type(4)));

#define T_ 5000
#define CAP 96  // bucket capacity; ovf path guarantees correctness on overflow

__device__ __forceinline__ u16 f2bf(float f) {
  u32 u = __float_as_uint(f);
  u += 0x7fffu + ((u >> 16) & 1u);
  return (u16)(u >> 16);
}

__device__ __forceinline__ void gload_lds16(const u16* g, u16* l) {
  __builtin_amdgcn_global_load_lds(
      (__attribute__((address_space(1))) void*)(u16*)g,
      (__attribute__((address_space(3))) void*)l, 16, 0, 0);
}

__device__ __forceinline__ u32 lds_off(const void* p) {
  return (u32)(uintptr_t)(__attribute__((address_space(3))) const void*)p;
}

// paired-row swizzle (R8-proven involution): byte (row, kb in [0,64)) ->
//   (row>>1)*128 + ((((row&1)<<6)|kb) ^ (((row>>1)&7)<<4))
__device__ __forceinline__ u32 swz(int row, int kb) {
  return (u32)((row >> 1) * 128 +
               ((((row & 1) << 6) | kb) ^ (((row >> 1) & 7) << 4)));
}

// Ws transpose (f32 [2][512][512] -> bf16 transposed) + zero bucket counters
__global__ void prep_k(const float* __restrict__ src, u16* __restrict__ dst,
                       int* __restrict__ cnt) {
  __shared__ float tile[32][33];
  const int tx = threadIdx.x, ty = threadIdx.y;
  const int a0 = blockIdx.x * 32;
  const int b0 = blockIdx.y * 32;
  const size_t zoff = (size_t)blockIdx.z * (512 * 512);
  const float* s = src + zoff;
  u16* d = dst + zoff;
#pragma unroll
  for (int r = 0; r < 4; ++r)
    tile[ty + r * 8][tx] = s[(size_t)(a0 + ty + r * 8) * 512 + b0 + tx];
  const int gid = ((blockIdx.z * 16 + blockIdx.y) * 16 + blockIdx.x) * 256 + ty * 32 + tx;
  if (gid < 5008) cnt[gid] = 0;
  __syncthreads();
#pragma unroll
  for (int r = 0; r < 4; ++r)
    d[(size_t)(b0 + ty + r * 8) * 512 + a0 + tx] = f2bf(tile[tx][ty + r * 8]);
}

// cd[t] = {col, bits(diag)}; bucket instance t into list[row]
__global__ void fill_k(const int* __restrict__ ev, const float* __restrict__ ui,
                       int2* __restrict__ cd, int* __restrict__ cnt,
                       int* __restrict__ list, int* __restrict__ ovf) {
  const int t = blockIdx.x * 256 + threadIdx.x;  // 0..32767
  const int r = ev[t] - 1;
  int2 v;
  v.x = r;
  v.y = __float_as_int(ui[(size_t)r * (T_ + 1)]);
  cd[t] = v;
  const int pos = atomicAdd(&cnt[r], 1);
  if (pos < CAP) list[r * CAP + pos] = t;
  else { const int o = atomicAdd(&cnt[5000], 1); ovf[o] = t; }
}

// one block per distinct ui row: stage row + instance list in LDS, serve 4-way.
__global__ __launch_bounds__(256)
void grow_gather(const float* __restrict__ ui, const int2* __restrict__ cd,
                 const int* __restrict__ cnt, const int* __restrict__ list,
                 const int* __restrict__ ovf, u16* __restrict__ adj) {
  __shared__ float row[5000];
  __shared__ int lst[CAP];
  const int r = blockIdx.x;
  int c = cnt[r];
  if (c > CAP) c = CAP;
  const int j = threadIdx.x * 2;
  if (c > 0) {
    const float* __restrict__ src = ui + (size_t)r * T_;
    for (int t = threadIdx.x; t < 1250; t += 256)
      *(float4*)&row[t * 4] = *(const float4*)&src[t * 4];
    if (threadIdx.x < c) lst[threadIdx.x] = list[r * CAP + threadIdx.x];
    __syncthreads();
    int q = 0;
    for (; q + 4 <= c; q += 4) {
      const int t0 = lst[q], t1 = lst[q + 1], t2 = lst[q + 2], t3 = lst[q + 3];
      const int4 p0 = *(const int4*)&cd[((t0 >> 9) << 9) + j];
      const int4 p1 = *(const int4*)&cd[((t1 >> 9) << 9) + j];
      const int4 p2 = *(const int4*)&cd[((t2 >> 9) << 9) + j];
      const int4 p3 = *(const int4*)&cd[((t3 >> 9) << 9) + j];
      const u32 k0 = (u32)f2bf(row[p0.x] + __int_as_float(p0.y)) |
                     ((u32)f2bf(row[p0.z] + __int_as_float(p0.w)) << 16);
      const u32 k1 = (u32)f2bf(row[p1.x] + __int_as_float(p1.y)) |
                     ((u32)f2bf(row[p1.z] + __int_as_float(p1.w)) << 16);
      const u32 k2 = (u32)f2bf(row[p2.x] + __int_as_float(p2.y)) |
                     ((u32)f2bf(row[p2.z] + __int_as_float(p2.w)) << 16);
      const u32 k3 = (u32)f2bf(row[p3.x] + __int_as_float(p3.y)) |
                     ((u32)f2bf(row[p3.z] + __int_as_float(p3.w)) << 16);
      *(u32*)&adj[(size_t)t0 * 512 + j] = k0;
      *(u32*)&adj[(size_t)t1 * 512 + j] = k1;
      *(u32*)&adj[(size_t)t2 * 512 + j] = k2;
      *(u32*)&adj[(size_t)t3 * 512 + j] = k3;
    }
    for (; q < c; ++q) {
      const int t0 = lst[q];
      const int4 p0 = *(const int4*)&cd[((t0 >> 9) << 9) + j];
      const u32 k0 = (u32)f2bf(row[p0.x] + __int_as_float(p0.y)) |
                     ((u32)f2bf(row[p0.z] + __int_as_float(p0.w)) << 16);
      *(u32*)&adj[(size_t)t0 * 512 + j] = k0;
    }
  }
  if (r < 8) {
    const int n = cnt[5000];
    for (int q = r; q < n; q += 8) {
      const int t = ovf[q];
      const long rr = (long)cd[t].x;
      const float* __restrict__ rp = ui + rr * (long)T_;
      const int4 p = *(const int4*)&cd[((t >> 9) << 9) + j];
      const u32 pk = (u32)f2bf(rp[p.x] + __int_as_float(p.y)) |
                     ((u32)f2bf(rp[p.z] + __int_as_float(p.w)) << 16);
      *(u32*)&adj[(size_t)t * 512 + j] = pk;
    }
  }
}

// ---------------------------------------------------------------------------
// fused_layer<LAYER>: per block (batch, 64-row i-stripe), two chained GEMMs:
//  Phase A: t[64 i][512 d] = adj_stripe @ x  (x: LAYER0 = enc f32 [l][d]
//           via reg-stage+cvt_pk convert; LAYER1 = xb bf16 [d][l] via
//           gload_lds). D[m=d][n=i] (swapped roles). t -> LDS bf16 (64 KB,
//           row-XOR swizzle), never touches HBM.
//  Phase B: y[64 i][512 e] = t @ W^T[e][d] (W staged depth-2 via gload_lds).
//           LAYER0: xb[e][i] = relu(y) (b64). LAYER1: mean partials P.
// LDS: t [0,64K); stage 2x32K [64K,128K); adj 2x4K [128K,136K). 16 k-steps
// per phase, stage-after-B2 depth-2, counted vmcnt (A: 17/L0, 5/L1; B: 4).
// Waves: 8. Phase A: wm=w>>1 (4 d-waves, 8 frags), wn=w&1 (2 i-waves, 2 frags).
// Phase B: we=w>>1 (4 e-waves, 8 frags), wi=w&1 (2 i-waves, 2 frags).
// ---------------------------------------------------------------------------
template <int LAYER>
__global__ __launch_bounds__(512, 2)
void fused_layer(const u16* __restrict__ adjG, const void* __restrict__ Xv,
                 const u16* __restrict__ wstL, void* __restrict__ outp) {
  extern __shared__ u16 smem[];
  const int tid = threadIdx.x;
  const int lane = tid & 63;
  const int w = tid >> 6;
  const int wg = blockIdx.x;
  const int mapped = (wg & 7) * 64 + (wg >> 3);  // chunked XCD swizzle, 512%8==0
  const int batch = mapped >> 3;
  const int stripe = mapped & 7;
  const size_t PS = (size_t)512 * 512;
  const u16* __restrict__ adjB = adjG + (size_t)batch * PS + (size_t)(stripe * 64) * 512;

  const int lr = lane & 15;
  const int kbB = (lane >> 4) << 4;
  const u32 ldsB = lds_off(smem);

  // 32-KB-tile staging chunks (x phase A L1 / W phase B): 4 chunks/thread
  u32 bigSrc[4], bigDstE[4];
#pragma unroll
  for (int r = 0; r < 4; ++r) {
    const int cc = r * 512 + tid;
    const int L = cc * 16;
    const int pp = L >> 7;
    const int off = (L & 127) ^ ((pp & 7) << 4);
    const int row = pp * 2 + (off >> 6);           // [0,512)
    bigSrc[r] = (u32)(row * 512 + ((off & 63) >> 1));
    bigDstE[r] = (u32)(32768 + (r * 512 + w * 64) * 8);  // elems (64 KB base)
  }
  // 4-KB adj tile: 1 chunk/thread, lanes<32 (uniform 1 vm-op per wave)
  u32 adjSrc, adjDstE;
  {
    const int cc = w * 32 + (lane & 31);
    const int L = cc * 16;
    const int pp = L >> 7;
    const int off = (L & 127) ^ ((pp & 7) << 4);
    const int row = pp * 2 + (off >> 6);           // [0,64)
    adjSrc = (u32)(row * 512 + ((off & 63) >> 1));
    adjDstE = (u32)(65536 + w * 256);              // elems (128 KB base)
  }

  // LAYER0 enc staging state: 16 dwordx2/thread/step (2 d-cols x 16 l)
  unsigned long long encB = 0;
  u32 boff0 = 0;
  u32x2 bs0[16], bs1[16];
  if (LAYER == 0) {
    encB = (unsigned long long)(uintptr_t)((const float*)Xv + (size_t)batch * PS);
    boff0 = (u32)((tid & 255) * 8 + (tid >> 8) * 32768);
  }
  const u16* __restrict__ xbS =
      (LAYER == 1) ? ((const u16*)Xv + (size_t)batch * PS) : (const u16*)nullptr;

#define BLOAD16(t, S)                                                        \
  {                                                                          \
    const u32 ob = boff0 + (u32)(t) * 65536u;                                \
    _Pragma("unroll") for (int i = 0; i < 16; ++i)                           \
        asm volatile("global_load_dwordx2 %0, %1, %2"                        \
                     : "=v"(S[i]) : "v"(ob + (u32)i * 2048u), "s"(encB));    \
  }

  // convert 32 f32 -> x region (rows d0=p*2, d0+1; l-halves), swizzled writes
#define CONV16(S)                                                            \
  {                                                                          \
    u32 we_[8], wo_[8];                                                      \
    _Pragma("unroll") for (int j = 0; j < 4; ++j) {                          \
      asm("v_cvt_pk_bf16_f32 %0, %1, %2" : "=v"(we_[j])                      \
          : "v"(S[2 * j].x), "v"(S[2 * j + 1].x));                           \
      asm("v_cvt_pk_bf16_f32 %0, %1, %2" : "=v"(we_[4 + j])                  \
          : "v"(S[8 + 2 * j].x), "v"(S[9 + 2 * j].x));                       \
      asm("v_cvt_pk_bf16_f32 %0, %1, %2" : "=v"(wo_[j])                      \
          : "v"(S[2 * j].y), "v"(S[2 * j + 1].y));                           \
      asm("v_cvt_pk_bf16_f32 %0, %1, %2" : "=v"(wo_[4 + j])                  \
          : "v"(S[8 + 2 * j].y), "v"(S[9 + 2 * j].y));                       \
    }                                                                        \
    const int p_ = tid & 255;                                                \
    const u32 X_ = (u32)((p_ & 7) << 4);                                     \
    const u32 lh_ = (u32)(tid >> 8) * 32u;                                   \
    char* rb_ = (char*)smem + 65536 + p_ * 128;                              \
    u32x4 v_;                                                                \
    v_.x = we_[0]; v_.y = we_[1]; v_.z = we_[2]; v_.w = we_[3];              \
    *(u32x4*)(rb_ + (lh_ ^ X_)) = v_;                                        \
    v_.x = we_[4]; v_.y = we_[5]; v_.z = we_[6]; v_.w = we_[7];              \
    *(u32x4*)(rb_ + ((lh_ + 16) ^ X_)) = v_;                                 \
    v_.x = wo_[0]; v_.y = wo_[1]; v_.z = wo_[2]; v_.w = wo_[3];              \
    *(u32x4*)(rb_ + ((64 + lh_) ^ X_)) = v_;                                 \
    v_.x = wo_[4]; v_.y = wo_[5]; v_.z = wo_[6]; v_.w = wo_[7];              \
    *(u32x4*)(rb_ + ((64 + lh_ + 16) ^ X_)) = v_;                            \
  }

  auto stageBig = [&](const u16* src, int t, int buf) {
#pragma unroll
    for (int r = 0; r < 4; ++r)
      gload_lds16(src + bigSrc[r] + t * 32, smem + bigDstE[r] + buf * 16384);
  };
  auto stageAdj = [&](int t, int buf) {
    if (lane < 32)
      gload_lds16(adjB + adjSrc + t * 32, smem + adjDstE + buf * 2048);
  };

  // ---- frag LDS byte offsets ----
  const int wmA = w >> 1, wnA = w & 1;
  u32 xOffA[8], adjOffA[2];
#pragma unroll
  for (int mf = 0; mf < 8; ++mf)
    xOffA[mf] = 65536u + swz(wmA * 128 + mf * 16 + lr, kbB);
#pragma unroll
  for (int nf = 0; nf < 2; ++nf)
    adjOffA[nf] = 131072u + swz(wnA * 32 + nf * 16 + lr, kbB);
  const int weB = w >> 1, wiB = w & 1;
  u32 wOffB[8], tRowB[2], tXB[2];
#pragma unroll
  for (int nf = 0; nf < 8; ++nf)
    wOffB[nf] = 65536u + swz(weB * 128 + nf * 16 + lr, kbB);
#pragma unroll
  for (int mf = 0; mf < 2; ++mf) {
    const int rowT = wiB * 32 + mf * 16 + lr;
    tRowB[mf] = (u32)(rowT * 1024);
    tXB[mf] = (u32)((rowT & 7) << 4);
  }

  // =================== PHASE A ===================
  f32x4 accA[8][2] = {};
  if (LAYER == 0) {
    BLOAD16(0, bs0); stageAdj(0, 0);
    BLOAD16(1, bs1); stageAdj(1, 1);
  } else {
    stageBig(xbS, 0, 0); stageAdj(0, 0);
    stageBig(xbS, 1, 1); stageAdj(1, 1);
  }

#pragma unroll
  for (int t = 0; t < 16; ++t) {
    if (t <= 14) {
      if (LAYER == 0) asm volatile("s_waitcnt vmcnt(17)" ::: "memory");
      else            asm volatile("s_waitcnt vmcnt(5)" ::: "memory");
    } else {
      asm volatile("s_waitcnt vmcnt(0)" ::: "memory");
    }
    __builtin_amdgcn_sched_barrier(0);
    if (LAYER == 0) {
      if (t & 1) { CONV16(bs1); } else { CONV16(bs0); }
      asm volatile("s_waitcnt lgkmcnt(0)" ::: "memory");  // drain own ds_writes
    }
    __builtin_amdgcn_s_barrier();  // B1: x(t)+adj(t) visible to all waves
    asm volatile("" ::: "memory");

    const u32 xb_ = ldsB + ((LAYER == 1) ? (u32)(t & 1) * 32768u : 0u);
    const u32 ab_ = ldsB + (u32)(t & 1) * 4096u;
    i32x4 xr[8], ar2[2];
#pragma unroll
    for (int m = 0; m < 8; ++m)
      asm volatile("ds_read_b128 %0, %1" : "=v"(xr[m]) : "v"(xb_ + xOffA[m]));
#pragma unroll
    for (int n = 0; n < 2; ++n)
      asm volatile("ds_read_b128 %0, %1" : "=v"(ar2[n]) : "v"(ab_ + adjOffA[n]));
    asm volatile("s_waitcnt lgkmcnt(0)" ::: "memory");
    __builtin_amdgcn_sched_barrier(0);

    __builtin_amdgcn_s_setprio(1);
#pragma unroll
    for (int m = 0; m < 8; ++m)
#pragma unroll
      for (int n = 0; n < 2; ++n)
        accA[m][n] = __builtin_amdgcn_mfma_f32_16x16x32_bf16(
            __builtin_bit_cast(bf16x8, xr[m]),
            __builtin_bit_cast(bf16x8, ar2[n]), accA[m][n], 0, 0, 0);
    __builtin_amdgcn_s_setprio(0);
    asm volatile("" ::: "memory");
    __builtin_amdgcn_s_barrier();  // B2: all reads of buf(t) done
    __builtin_amdgcn_sched_barrier(0);
    if (t + 2 < 16) {
      if (LAYER == 0) { if (t & 1) { BLOAD16(t + 2, bs1); } else { BLOAD16(t + 2, bs0); } }
      else stageBig(xbS, t + 2, t & 1);
      stageAdj(t + 2, t & 1);
    }
  }

  // t -> LDS (bf16, row-XOR swizzle). D[m=d][n=i]: lane holds t[ii][dd..dd+3]
#pragma unroll
  for (int nf = 0; nf < 2; ++nf)
#pragma unroll
    for (int mf = 0; mf < 8; ++mf) {
      const int ii = wnA * 32 + nf * 16 + lr;
      const int dd = wmA * 128 + mf * 16 + (lane >> 4) * 4;
      const f32x4 v = accA[mf][nf];
      uint2 p;
      p.x = (u32)f2bf(v[0]) | ((u32)f2bf(v[1]) << 16);
      p.y = (u32)f2bf(v[2]) | ((u32)f2bf(v[3]) << 16);
      *(uint2*)((char*)smem + ii * 1024 + ((dd * 2) ^ ((ii & 7) << 4))) = p;
    }
  __syncthreads();
  __builtin_amdgcn_sched_barrier(0);

  // =================== PHASE B ===================
  f32x4 accB[2][8] = {};
  stageBig(wstL, 0, 0);
  stageBig(wstL, 1, 1);

#pragma unroll
  for (int t = 0; t < 16; ++t) {
    if (t <= 14) asm volatile("s_waitcnt vmcnt(4)" ::: "memory");
    else         asm volatile("s_waitcnt vmcnt(0)" ::: "memory");
    __builtin_amdgcn_sched_barrier(0);
    __builtin_amdgcn_s_barrier();  // B1: W(t) visible
    asm volatile("" ::: "memory");

    const u32 wb_ = ldsB + (u32)(t & 1) * 32768u;
    i32x4 tr[2], wr8[8];
#pragma unroll
    for (int mf = 0; mf < 2; ++mf) {
      const u32 byt = ldsB + tRowB[mf] + (((u32)(t * 64) + (u32)kbB) ^ tXB[mf]);
      asm volatile("ds_read_b128 %0, %1" : "=v"(tr[mf]) : "v"(byt));
    }
#pragma unroll
    for (int nf = 0; nf < 8; ++nf)
      asm volatile("ds_read_b128 %0, %1" : "=v"(wr8[nf]) : "v"(wb_ + wOffB[nf]));
    asm volatile("s_waitcnt lgkmcnt(0)" ::: "memory");
    __builtin_amdgcn_sched_barrier(0);

    __builtin_amdgcn_s_setprio(1);
#pragma unroll
    for (int mf = 0; mf < 2; ++mf)
#pragma unroll
      for (int nf = 0; nf < 8; ++nf)
        accB[mf][nf] = __builtin_amdgcn_mfma_f32_16x16x32_bf16(
            __builtin_bit_cast(bf16x8, tr[mf]),
            __builtin_bit_cast(bf16x8, wr8[nf]), accB[mf][nf], 0, 0, 0);
    __builtin_amdgcn_s_setprio(0);
    asm volatile("" ::: "memory");
    __builtin_amdgcn_s_barrier();  // B2
    __builtin_amdgcn_sched_barrier(0);
    if (t + 2 < 16) stageBig(wstL, t + 2, t & 1);
  }

  // epilogue: D[m=i][n=e]
  if (LAYER == 0) {
    u16* __restrict__ xbO = (u16*)outp + (size_t)batch * PS;
#pragma unroll
    for (int mf = 0; mf < 2; ++mf)
#pragma unroll
      for (int nf = 0; nf < 8; ++nf) {
        const int e = weB * 128 + nf * 16 + lr;
        const int iloc = wiB * 32 + mf * 16 + (lane >> 4) * 4;
        const f32x4 v = accB[mf][nf];
        uint2 p;
        p.x = (u32)f2bf(fmaxf(v[0], 0.f)) | ((u32)f2bf(fmaxf(v[1], 0.f)) << 16);
        p.y = (u32)f2bf(fmaxf(v[2], 0.f)) | ((u32)f2bf(fmaxf(v[3], 0.f)) << 16);
        *(uint2*)&xbO[(size_t)e * 512 + stripe * 64 + iloc] = p;
      }
  } else {
    float* __restrict__ Pp = (float*)outp;
#pragma unroll
    for (int nf = 0; nf < 8; ++nf) {
      float s = 0.f;
#pragma unroll
      for (int mf = 0; mf < 2; ++mf) {
        const f32x4 v = accB[mf][nf];
#pragma unroll
        for (int j = 0; j < 4; ++j) s += fmaxf(v[j], 0.f);
      }
      s += __shfl_xor(s, 16);
      s += __shfl_xor(s, 32);
      if ((lane >> 4) == 0) {
        const int e = weB * 128 + nf * 16 + lane;
        Pp[((size_t)(batch * 16 + stripe * 2 + wiB)) * 512 + e] = s;
      }
    }
  }
#undef BLOAD16
#undef CONV16
}

// out[b,d] = (1/512) * sum_{16 slots} P[b][slot][d]
__global__ void reduce_mean(const float* __restrict__ P, float* __restrict__ out) {
  const int t = blockIdx.x * 256 + threadIdx.x;
  const int b = t >> 9, d = t & 511;
  float s = 0.f;
#pragma unroll
  for (int q = 0; q < 16; ++q) s += P[((size_t)b * 16 + q) * 512 + d];
  out[t] = s * (1.0f / 512.0f);
}

extern "C" void kernel_launch(void* const* d_in, const int* in_sizes, int n_in,
                              void* d_out, int out_size, void* d_ws, size_t ws_size,
                              hipStream_t stream) {
  const float* enc = (const float*)d_in[0];   // (64,512,512) f32
  const float* ui  = (const float*)d_in[1];   // (5000,5000) f32
  const float* Ws  = (const float*)d_in[2];   // (2,512,512) f32
  const int*   ev  = (const int*)d_in[3];     // (64,512) int
  float* out = (float*)d_out;                 // (64,512) f32

  char* ws = (char*)d_ws;
  const size_t SLAB = (size_t)64 * 512 * 512 * 2;  // 32 MiB
  u16* adj = (u16*)(ws);
  u16* xb  = (u16*)(ws + SLAB);
  char* p = ws + 2 * SLAB;
  u16* wst  = (u16*)p;  p += (size_t)2 * 512 * 512 * 2;
  int2* cd  = (int2*)p; p += (size_t)32768 * 8;
  int* cnt  = (int*)p;  p += 5008 * 4;
  int* list = (int*)p;  p += (size_t)5000 * CAP * 4;
  int* ovf  = (int*)p;  p += (size_t)32768 * 4;
  float* P  = (float*)p;                               // [64][16][512] f32, 2 MB

  const size_t PS = (size_t)512 * 512;
  const size_t SMEM = 139264;  // t 64K + stage 2x32K + adj 2x4K
  (void)hipFuncSetAttribute(reinterpret_cast<const void*>(fused_layer<0>),
                            hipFuncAttributeMaxDynamicSharedMemorySize, (int)SMEM);
  (void)hipFuncSetAttribute(reinterpret_cast<const void*>(fused_layer<1>),
                            hipFuncAttributeMaxDynamicSharedMemorySize, (int)SMEM);

  prep_k<<<dim3(16, 16, 2), dim3(32, 8), 0, stream>>>(Ws, wst, cnt);
  fill_k<<<128, 256, 0, stream>>>(ev, ui, cd, cnt, list, ovf);
  grow_gather<<<5000, 256, 0, stream>>>(ui, cd, cnt, list, ovf, adj);
  // layer 0: xb = relu((adj @ enc) @ W0)   (t never leaves LDS)
  fused_layer<0><<<512, 512, SMEM, stream>>>(adj, enc, wst, xb);
  // layer 1: P partials of relu((adj @ xb) @ W1)
  fused_layer<1><<<512, 512, SMEM, stream>>>(adj, xb, wst + PS, P);
  reduce_mean<<<128, 256, 0, stream>>>(P, out);
}

// Round 12
// 140.355 us; speedup vs baseline: 1.1675x; 1.1675x over previous
//
#include <hip/hip_runtime.h>

typedef unsigned short u16;
typedef unsigned int u32;
typedef __bf16 bf16x8 __attribute__((ext_vector_type(8)));
typedef float f32x4 __attribute__((ext_vector_type(4)));
typedef int i32x4 __attribute__((ext_vector_type(4)));
typedef u32 u32x2 __attribute__((ext_vector_type(2)));
typedef u32 u32x4 __attribute__((ext_vector_type(4)));

#define T_ 5000
#define CAP 96  // bucket capacity; ovf kernel guarantees correctness on overflow

__device__ __forceinline__ u16 f2bf(float f) {
  u32 u = __float_as_uint(f);
  u += 0x7fffu + ((u >> 16) & 1u);
  return (u16)(u >> 16);
}
__device__ __forceinline__ float bf2f(u32 bits16) {
  return __uint_as_float(bits16 << 16);
}

__device__ __forceinline__ void gload_lds16(const u16* g, u16* l) {
  __builtin_amdgcn_global_load_lds(
      (__attribute__((address_space(1))) void*)(u16*)g,
      (__attribute__((address_space(3))) void*)l, 16, 0, 0);
}

__device__ __forceinline__ u32 lds_off(const void* p) {
  return (u32)(uintptr_t)(__attribute__((address_space(3))) const void*)p;
}

// f32 [Z][512][512] -> bf16 [Z][512][512] transposed (used for Ws only)
__global__ void transpose_cast(const float* __restrict__ src, u16* __restrict__ dst) {
  __shared__ float tile[32][33];
  const int tx = threadIdx.x, ty = threadIdx.y;
  const int a0 = blockIdx.x * 32;
  const int b0 = blockIdx.y * 32;
  const size_t zoff = (size_t)blockIdx.z * (512 * 512);
  const float* s = src + zoff;
  u16* d = dst + zoff;
#pragma unroll
  for (int r = 0; r < 4; ++r)
    tile[ty + r * 8][tx] = s[(size_t)(a0 + ty + r * 8) * 512 + b0 + tx];
  __syncthreads();
#pragma unroll
  for (int r = 0; r < 4; ++r)
    d[(size_t)(b0 + ty + r * 8) * 512 + a0 + tx] = f2bf(tile[tx][ty + r * 8]);
}

__global__ void zero_k(int* __restrict__ cnt) {
  const int t = blockIdx.x * 256 + threadIdx.x;
  if (t < 5001) cnt[t] = 0;
}

// cd[t] = {col, bits(diag)}; bucket instance t into list[row]
__global__ void fill_k(const int* __restrict__ ev, const float* __restrict__ ui,
                       int2* __restrict__ cd, int* __restrict__ cnt,
                       int* __restrict__ list, int* __restrict__ ovf) {
  const int t = blockIdx.x * 256 + threadIdx.x;  // 0..32767
  const int r = ev[t] - 1;
  int2 v;
  v.x = r;
  v.y = __float_as_int(ui[(size_t)r * (T_ + 1)]);
  cd[t] = v;
  const int pos = atomicAdd(&cnt[r], 1);
  if (pos < CAP) list[r * CAP + pos] = t;
  else { const int o = atomicAdd(&cnt[5000], 1); ovf[o] = t; }
}

// one block per distinct ui row: stage row in LDS, serve instances (2-way ILP)
__global__ __launch_bounds__(256)
void grow_gather(const float* __restrict__ ui, const int2* __restrict__ cd,
                 const int* __restrict__ cnt, const int* __restrict__ list,
                 u16* __restrict__ adj) {
  const int r = blockIdx.x;
  int c = cnt[r];
  if (c <= 0) return;
  if (c > CAP) c = CAP;
  __shared__ float row[5000];
  const float* __restrict__ src = ui + (size_t)r * T_;
  for (int t = threadIdx.x; t < 1250; t += 256)
    *(float4*)&row[t * 4] = *(const float4*)&src[t * 4];
  __syncthreads();
  const int j = threadIdx.x * 2;
  const int lb = r * CAP;
  int q = 0;
  for (; q + 2 <= c; q += 2) {
    const int t0 = list[lb + q], t1 = list[lb + q + 1];
    const int b0 = (t0 >> 9) << 9, b1 = (t1 >> 9) << 9;
    const int4 p0 = *(const int4*)&cd[b0 + j];
    const int4 p1 = *(const int4*)&cd[b1 + j];
    const u32 pk0 = (u32)f2bf(row[p0.x] + __int_as_float(p0.y)) |
                    ((u32)f2bf(row[p0.z] + __int_as_float(p0.w)) << 16);
    const u32 pk1 = (u32)f2bf(row[p1.x] + __int_as_float(p1.y)) |
                    ((u32)f2bf(row[p1.z] + __int_as_float(p1.w)) << 16);
    *(u32*)&adj[(size_t)t0 * 512 + j] = pk0;
    *(u32*)&adj[(size_t)t1 * 512 + j] = pk1;
  }
  if (q < c) {
    const int t0 = list[lb + q];
    const int b0 = (t0 >> 9) << 9;
    const int4 p0 = *(const int4*)&cd[b0 + j];
    const u32 pk0 = (u32)f2bf(row[p0.x] + __int_as_float(p0.y)) |
                    ((u32)f2bf(row[p0.z] + __int_as_float(p0.w)) << 16);
    *(u32*)&adj[(size_t)t0 * 512 + j] = pk0;
  }
}

__global__ void ovf_gather(const float* __restrict__ ui, const int2* __restrict__ cd,
                           const int* __restrict__ cnt, const int* __restrict__ ovf,
                           u16* __restrict__ adj) {
  const int n = cnt[5000];
  for (int q = blockIdx.x; q < n; q += gridDim.x) {
    const int t = ovf[q];
    const int base = (t >> 9) << 9;
    const long r = (long)cd[t].x;
    const float* __restrict__ row = ui + r * (long)T_;
    const int j = threadIdx.x * 2;
    const int4 p = *(const int4*)&cd[base + j];
    const u32 pk = (u32)f2bf(row[p.x] + __int_as_float(p.y)) |
                   ((u32)f2bf(row[p.z] + __int_as_float(p.w)) << 16);
    *(u32*)&adj[(size_t)t * 512 + j] = pk;
  }
}

// ---------------------------------------------------------------------------
// 256x256-tile GEMM, BK=32, 8 waves (2Mx4N), wave tile 128x64.
// BSRC 0: B bf16 n-major [n][k] via gload_lds, 4 LDS B-buffers.
// BSRC 1: B f32 k-major [k][n] (enc direct): reg-staged asm loads + cvt_pk +
//         swizzled ds_write_b128 into a single 16KB n-major B buffer.
// MODE 0: C row-major bf16. MODE 1: C transposed + relu. MODE 2: relu+col-sum
// partials P[b][slot][d].
// LDS swizzle (involution): tile byte (row, kb) at (row>>1)*128 +
//   ((((row&1)<<6)|kb) ^ (((row>>1)&7)<<4)).
// ---------------------------------------------------------------------------
template <int MODE, int BSRC>
__global__ __launch_bounds__(512, 2)
void gemm256(const u16* __restrict__ A, const void* __restrict__ Bv,
             u16* __restrict__ C, size_t strideA, size_t strideB, size_t strideC,
             float* __restrict__ P) {
  extern __shared__ u16 smem[];  // A: 4 x 16KB @ [0,64K); B: @ [64K, ...)
  const int tid = threadIdx.x;
  const int lane = tid & 63;
  const int w = tid >> 6;
  const int wm = w >> 2, wn = w & 3;
  const int chunk = gridDim.x >> 3;
  const int wg = blockIdx.x;
  const int mapped = (wg & 7) * chunk + (wg >> 3);
  const int batch = mapped >> 2;
  const int tm = (mapped >> 1) & 1, tn = mapped & 1;
  const int m0 = tm << 8, n0 = tn << 8;
  const u16* __restrict__ Ab = A + (size_t)batch * strideA;

  // A staging: chunk c = r*512+tid (16B); inverse-swizzle to tile coords
  const u16* gA[2];
  u32 ldA[2];
#pragma unroll
  for (int r = 0; r < 2; ++r) {
    const int c = r * 512 + tid;
    const int L = c * 16;
    const int pp = L >> 7;
    const int off = (L & 127) ^ ((pp & 7) << 4);
    const int m = pp * 2 + (off >> 6);
    const int kb = off & 63;
    gA[r] = Ab + (size_t)(m0 + m) * 512 + (kb >> 1);
    ldA[r] = (u32)((r * 512 + w * 64) * 8);  // u16 elems; +lane*16B by HW
  }

  // BSRC0 staging state
  const u16* gB[2] = {nullptr, nullptr};
  u32 ldB[2] = {0, 0};
  if (BSRC == 0) {
    const u16* __restrict__ Bb = (const u16*)Bv + (size_t)batch * strideB;
#pragma unroll
    for (int r = 0; r < 2; ++r) {
      const int c = r * 512 + tid;
      const int L = c * 16;
      const int pp = L >> 7;
      const int off = (L & 127) ^ ((pp & 7) << 4);
      const int m = pp * 2 + (off >> 6);
      const int kb = off & 63;
      gB[r] = Bb + (size_t)(n0 + m) * 512 + (kb >> 1);
      ldB[r] = (u32)(32768 + (r * 512 + w * 64) * 8);
    }
  }

  // BSRC1 staging state: 8 l x 2 d per thread
  const int dp = tid & 127;           // (w&1)*64 + lane
  const int lq = tid >> 7;            // l-quarter (== w>>1)
  unsigned long long encB = 0;
  u32 boff0 = 0;
  u32x2 bs0[8], bs1[8];
  if (BSRC == 1) {
    encB = (unsigned long long)(uintptr_t)((const float*)Bv + (size_t)batch * strideB);
    boff0 = (u32)(((lq * 8) * 512 + n0 + dp * 2) * 4);
  }

#define BLOAD(t, S)                                                          \
  {                                                                          \
    const u32 ob = boff0 + (u32)(t) * 65536u;                                \
    _Pragma("unroll") for (int i = 0; i < 8; ++i)                            \
        asm volatile("global_load_dwordx2 %0, %1, %2"                        \
                     : "=v"(S[i])                                            \
                     : "v"(ob + (u32)i * 2048u), "s"(encB));                 \
  }

#define CONVERT_B(S)                                                         \
  {                                                                          \
    u32 wrd0[4], wrd1[4];                                                    \
    _Pragma("unroll") for (int jj = 0; jj < 4; ++jj) {                       \
      asm("v_cvt_pk_bf16_f32 %0, %1, %2"                                     \
          : "=v"(wrd0[jj]) : "v"(S[2 * jj].x), "v"(S[2 * jj + 1].x));        \
      asm("v_cvt_pk_bf16_f32 %0, %1, %2"                                     \
          : "=v"(wrd1[jj]) : "v"(S[2 * jj].y), "v"(S[2 * jj + 1].y));        \
    }                                                                        \
    const u32 by0 = (u32)dp * 128u + ((((u32)lq * 16u)) ^ (((u32)dp & 7u) << 4)); \
    const u32 by1 = (u32)dp * 128u + ((64u | ((u32)lq * 16u)) ^ (((u32)dp & 7u) << 4)); \
    u32x4 v0, v1;                                                            \
    v0.x = wrd0[0]; v0.y = wrd0[1]; v0.z = wrd0[2]; v0.w = wrd0[3];          \
    v1.x = wrd1[0]; v1.y = wrd1[1]; v1.z = wrd1[2]; v1.w = wrd1[3];          \
    *(u32x4*)((char*)smem + 65536 + by0) = v0;                               \
    *(u32x4*)((char*)smem + 65536 + by1) = v1;                               \
  }

  // frag LDS byte offsets
  const int lr = lane & 15;
  const int kb = (lane >> 4) << 4;
  u32 aOff[8], bOff[4];
#pragma unroll
  for (int m = 0; m < 8; ++m) {
    const int row = wm * 128 + m * 16 + lr;
    aOff[m] = (u32)((row >> 1) * 128 + ((((row & 1) << 6) | kb) ^ (((row >> 1) & 7) << 4)));
  }
#pragma unroll
  for (int n = 0; n < 4; ++n) {
    const int row = wn * 64 + n * 16 + lr;
    bOff[n] = (u32)(65536 + (row >> 1) * 128 + ((((row & 1) << 6) | kb) ^ (((row >> 1) & 7) << 4)));
  }
  const u32 ldsBase = lds_off(smem);

  f32x4 acc[8][4] = {};

  auto stageA = [&](int t) {
    const u32 bo = (u32)(t & 3) * 8192;
#pragma unroll
    for (int r = 0; r < 2; ++r) gload_lds16(gA[r] + t * 32, smem + bo + ldA[r]);
  };
  auto stageB0 = [&](int t) {
    const u32 bo = (u32)(t & 3) * 8192;
#pragma unroll
    for (int r = 0; r < 2; ++r) gload_lds16(gB[r] + t * 32, smem + bo + ldB[r]);
  };

  if (BSRC == 0) {
    stageA(0); stageB0(0); stageA(1); stageB0(1); stageA(2); stageB0(2);
  } else {
    stageA(0); stageA(1); stageA(2);
    BLOAD(0, bs0); BLOAD(1, bs1);
  }

#pragma unroll
  for (int t = 0; t < 16; ++t) {
    if (BSRC == 0) {
      if (t <= 13)      asm volatile("s_waitcnt vmcnt(8)" ::: "memory");
      else if (t == 14) asm volatile("s_waitcnt vmcnt(4)" ::: "memory");
      else              asm volatile("s_waitcnt vmcnt(0)" ::: "memory");
      __builtin_amdgcn_sched_barrier(0);
      if (t + 3 < 16) { stageA(t + 3); stageB0(t + 3); }
      asm volatile("" ::: "memory");
      __builtin_amdgcn_s_barrier();  // B1
      asm volatile("" ::: "memory");
    } else {
      if (t == 0)              asm volatile("s_waitcnt vmcnt(8)" ::: "memory");
      else if (t <= 13)        asm volatile("s_waitcnt vmcnt(10)" ::: "memory");
      else if (t == 14)        asm volatile("s_waitcnt vmcnt(8)" ::: "memory");
      else                     asm volatile("s_waitcnt vmcnt(0)" ::: "memory");
      __builtin_amdgcn_sched_barrier(0);
      if (t & 1) { CONVERT_B(bs1); } else { CONVERT_B(bs0); }
      if (t + 3 < 16) stageA(t + 3);
      if (t + 2 < 16) { if (t & 1) { BLOAD(t + 2, bs1); } else { BLOAD(t + 2, bs0); } }
      asm volatile("s_waitcnt lgkmcnt(0)" ::: "memory");  // drain my ds_writes
      __builtin_amdgcn_s_barrier();  // B1
      asm volatile("" ::: "memory");
    }

    const u32 abase = ldsBase + (u32)(t & 3) * 16384;
    const u32 bbase = (BSRC == 0) ? (ldsBase + (u32)(t & 3) * 16384) : ldsBase;
    i32x4 araw[8], braw[4];
#pragma unroll
    for (int m = 0; m < 8; ++m)
      asm volatile("ds_read_b128 %0, %1" : "=v"(araw[m]) : "v"(abase + aOff[m]));
#pragma unroll
    for (int n = 0; n < 4; ++n)
      asm volatile("ds_read_b128 %0, %1" : "=v"(braw[n]) : "v"(bbase + bOff[n]));
    asm volatile("s_waitcnt lgkmcnt(0)" ::: "memory");
    __builtin_amdgcn_sched_barrier(0);

    __builtin_amdgcn_s_setprio(1);
#pragma unroll
    for (int m = 0; m < 8; ++m)
#pragma unroll
      for (int n = 0; n < 4; ++n)
        acc[m][n] = __builtin_amdgcn_mfma_f32_16x16x32_bf16(
            __builtin_bit_cast(bf16x8, araw[m]),
            __builtin_bit_cast(bf16x8, braw[n]), acc[m][n], 0, 0, 0);
    __builtin_amdgcn_s_setprio(0);
    asm volatile("" ::: "memory");
    __builtin_amdgcn_s_barrier();  // B2
    __builtin_amdgcn_sched_barrier(0);
  }
#undef BLOAD
#undef CONVERT_B

  u16* Cb = C + (size_t)batch * strideC;
  if (MODE == 0) {
#pragma unroll
    for (int m = 0; m < 8; ++m) {
      const int row = m0 + wm * 128 + m * 16 + (lane >> 4) * 4;
#pragma unroll
      for (int n = 0; n < 4; ++n) {
        const int col = n0 + wn * 64 + n * 16 + (lane & 15);
        const f32x4 v = acc[m][n];
#pragma unroll
        for (int j = 0; j < 4; ++j)
          Cb[(size_t)(row + j) * 512 + col] = f2bf(v[j]);
      }
    }
  } else if (MODE == 1) {
#pragma unroll
    for (int m = 0; m < 8; ++m) {
      const int i = m0 + wm * 128 + m * 16 + (lane >> 4) * 4;
#pragma unroll
      for (int n = 0; n < 4; ++n) {
        const int d = n0 + wn * 64 + n * 16 + (lane & 15);
        const f32x4 v = acc[m][n];
        uint2 p;
        p.x = (u32)f2bf(fmaxf(v[0], 0.f)) | ((u32)f2bf(fmaxf(v[1], 0.f)) << 16);
        p.y = (u32)f2bf(fmaxf(v[2], 0.f)) | ((u32)f2bf(fmaxf(v[3], 0.f)) << 16);
        *(uint2*)&Cb[(size_t)d * 512 + i] = p;
      }
    }
  } else {
    const int slot = tm * 2 + wm;
#pragma unroll
    for (int n = 0; n < 4; ++n) {
      float s = 0.f;
#pragma unroll
      for (int m = 0; m < 8; ++m) {
        const f32x4 v = acc[m][n];
#pragma unroll
        for (int j = 0; j < 4; ++j) s += fmaxf(v[j], 0.f);
      }
      s += __shfl_xor(s, 16);
      s += __shfl_xor(s, 32);
      if ((lane >> 4) == 0) {
        const int d = n0 + wn * 64 + n * 16 + lane;
        P[((size_t)batch * 4 + slot) * 512 + d] = s;
      }
    }
  }
}

// out[b,d] = (1/512) * sum_slot P[b][slot][d]
__global__ void reduce_mean(const float* __restrict__ P, float* __restrict__ out) {
  const int t = blockIdx.x * 256 + threadIdx.x;
  const int b = t >> 9, d = t & 511;
  float s = 0.f;
#pragma unroll
  for (int q = 0; q < 4; ++q) s += P[((size_t)b * 4 + q) * 512 + d];
  out[t] = s * (1.0f / 512.0f);
}

extern "C" void kernel_launch(void* const* d_in, const int* in_sizes, int n_in,
                              void* d_out, int out_size, void* d_ws, size_t ws_size,
                              hipStream_t stream) {
  const float* enc = (const float*)d_in[0];   // (64,512,512) f32, [l][d] = k-major
  const float* ui  = (const float*)d_in[1];   // (5000,5000) f32
  const float* Ws  = (const float*)d_in[2];   // (2,512,512) f32
  const int*   ev  = (const int*)d_in[3];     // (64,512) int
  float* out = (float*)d_out;                 // (64,512) f32

  char* ws = (char*)d_ws;
  const size_t SLAB = (size_t)64 * 512 * 512 * 2;  // 32 MiB
  u16* adj  = (u16*)(ws);
  u16* tbuf = (u16*)(ws + SLAB);
  u16* xb   = (u16*)(ws + 2 * SLAB);
  char* p = ws + 3 * SLAB;
  u16* wst  = (u16*)p;  p += (size_t)2 * 512 * 512 * 2;
  int2* cd  = (int2*)p; p += (size_t)32768 * 8;
  int* cnt  = (int*)p;  p += 5008 * 4;
  int* list = (int*)p;  p += (size_t)5000 * CAP * 4;
  int* ovf  = (int*)p;  p += (size_t)32768 * 4;
  float* P  = (float*)p;                               // [64][4][512] f32

  const size_t PS = (size_t)512 * 512;
  const size_t SMEM0 = 131072;  // BSRC0: A 4x16K + B 4x16K
  const size_t SMEM1 = 81920;   // BSRC1: A 4x16K + B 1x16K
  (void)hipFuncSetAttribute(reinterpret_cast<const void*>(gemm256<0, 1>),
                            hipFuncAttributeMaxDynamicSharedMemorySize, (int)SMEM1);
  (void)hipFuncSetAttribute(reinterpret_cast<const void*>(gemm256<1, 0>),
                            hipFuncAttributeMaxDynamicSharedMemorySize, (int)SMEM0);
  (void)hipFuncSetAttribute(reinterpret_cast<const void*>(gemm256<0, 0>),
                            hipFuncAttributeMaxDynamicSharedMemorySize, (int)SMEM0);
  (void)hipFuncSetAttribute(reinterpret_cast<const void*>(gemm256<2, 0>),
                            hipFuncAttributeMaxDynamicSharedMemorySize, (int)SMEM0);

  zero_k<<<20, 256, 0, stream>>>(cnt);
  fill_k<<<128, 256, 0, stream>>>(ev, ui, cd, cnt, list, ovf);
  transpose_cast<<<dim3(16, 16, 2), dim3(32, 8), 0, stream>>>(Ws, wst);
  grow_gather<<<5000, 256, 0, stream>>>(ui, cd, cnt, list, adj);
  ovf_gather<<<8, 256, 0, stream>>>(ui, cd, cnt, ovf, adj);
  // layer 0: t = adj @ enc  (B = f32 k-major enc, fused cast)
  gemm256<0, 1><<<256, 512, SMEM1, stream>>>(adj, enc, tbuf, PS, PS, PS, nullptr);
  gemm256<1, 0><<<256, 512, SMEM0, stream>>>(tbuf, wst, xb, PS, 0, PS, nullptr);
  // layer 1 (+ fused mean partials)
  gemm256<0, 0><<<256, 512, SMEM0, stream>>>(adj, xb, tbuf, PS, PS, PS, nullptr);
  gemm256<2, 0><<<256, 512, SMEM0, stream>>>(tbuf, wst + PS, nullptr, PS, 0, 0, P);
  reduce_mean<<<128, 256, 0, stream>>>(P, out);
}